// Round 13
// baseline (426.849 us; speedup 1.0000x reference)
//
#include <hip/hip_runtime.h>
#include <stdint.h>

#define NN 1024
#define DD 256
#define KHOPS 8

typedef unsigned short u16;
typedef unsigned long long u64;
typedef unsigned char u8;

__device__ __forceinline__ float b2f(u16 u){ return __uint_as_float(((unsigned int)u) << 16); }
__device__ __forceinline__ u16 f2b(float f){
  unsigned int x = __float_as_uint(f);
  unsigned int r = (x + 0x7FFFu + ((x >> 16) & 1u)) >> 16;
  return (u16)r;
}
__device__ __forceinline__ float wsum(float v){
  #pragma unroll
  for(int off = 32; off >= 1; off >>= 1) v += __shfl_xor(v, off, 64);
  return v;
}

// ---------------- sentinel fill (contract-violation signal), f32
__global__ __launch_bounds__(256) void k_fill(float* p, unsigned n, float v){
  unsigned idx = blockIdx.x * 256 + threadIdx.x;
  if(idx < n) p[idx] = v;
}

// ---------------- adjacency int32 -> bitset
__global__ __launch_bounds__(256) void k_bitset(const int* adj, u64* bits){
  int row = blockIdx.x * 4 + (threadIdx.x >> 6);
  int lane = threadIdx.x & 63;
  const int* ar = adj + (size_t)row * NN;
  #pragma unroll
  for(int w = 0; w < 16; w++){
    u64 msk = __ballot(ar[w * 64 + lane] != 0);
    if(lane == 0) bits[(size_t)row * 16 + w] = msk;
  }
}

// ---------------- frontier BFS, register-resident, shfl-butterfly frontier OR
__global__ __launch_bounds__(64) void k_bfs(const u64* bits, u8* dist, float* expl){
  int row = blockIdx.x;                 // b*N + i
  int b = row >> 10;
  int lane = threadIdx.x;
  __shared__ __attribute__((aligned(16))) u8 drow[NN];
  const u64* bb = bits + ((size_t)(b << 10)) * 16;
  const u64* myrow = bits + (size_t)row * 16;
  u64 vis[16], cur[16];
  #pragma unroll
  for(int w = 0; w < 16; w++){ u64 v = myrow[w]; vis[w] = v; cur[w] = v; }
  { int4 ff; ff.x = ff.y = ff.z = ff.w = -1; ((int4*)drow)[lane] = ff; }
  __syncthreads();
  #pragma unroll
  for(int it = 0; it < 16; it++)
    if((cur[it] >> lane) & 1) drow[it * 64 + lane] = 0;
  for(int k = 1; k < KHOPS; k++){
    u64 acc[16];
    #pragma unroll
    for(int w = 0; w < 16; w++) acc[w] = 0;
    #pragma unroll
    for(int it = 0; it < 16; it++){
      if((cur[it] >> lane) & 1){
        const u64* r = bb + (size_t)(it * 64 + lane) * 16;
        #pragma unroll
        for(int w = 0; w < 16; w++) acc[w] |= r[w];
      }
    }
    #pragma unroll
    for(int mask = 32; mask >= 1; mask >>= 1){
      #pragma unroll
      for(int w = 0; w < 16; w++) acc[w] |= __shfl_xor(acc[w], mask, 64);
    }
    u64 any = 0;
    #pragma unroll
    for(int w = 0; w < 16; w++){
      u64 nw = acc[w] & ~vis[w];
      vis[w] |= nw;
      cur[w] = nw;
      any |= nw;
    }
    if(any == 0) break;                          // wave-uniform
    #pragma unroll
    for(int it = 0; it < 16; it++)
      if((cur[it] >> lane) & 1) drow[it * 64 + lane] = (u8)k;
  }
  __syncthreads();
  ((int4*)(dist + (size_t)row * NN))[lane] = ((const int4*)drow)[lane];
  float* eo = expl + (size_t)row * NN;
  #pragma unroll
  for(int it = 0; it < 16; it++){
    int j = it * 64 + lane;
    eo[j] = ((vis[it] >> lane) & 1) ? 1.0f : 0.0f;
  }
}

// ---------------- att_bias = ea + weight[dist] (f32) + fusion numerators fvals (f32, exact)
__global__ __launch_bounds__(256) void k_bias(const float* ea, const u8* dist, const float* dw,
                                              float* ab_out, float* fvals){
  __shared__ float w8s[4][8];
  int wv = threadIdx.x >> 6, lane = threadIdx.x & 63;
  int widx = blockIdx.x * 4 + wv;
  int i = widx & 1023, b = widx >> 13;
  int h = (widx >> 10) & 7;
  int bn_i = (b << 10) + i;
  if(lane < 8) w8s[wv][lane] = dw[lane * 8 + h];
  __syncthreads();
  const float* earow = ea + (size_t)widx * NN;
  const u8* drow = dist + (size_t)bn_i * NN;
  float* abrow = ab_out + (size_t)widx * NN;
  int c0 = lane << 4;
  int4 d4 = *(const int4*)(drow + c0);
  unsigned dws[4] = {(unsigned)d4.x,(unsigned)d4.y,(unsigned)d4.z,(unsigned)d4.w};
  float fpart = 0.f;
  #pragma unroll
  for(int g = 0; g < 4; g++){
    float4 e = *(const float4*)(earow + c0 + g * 4);
    float vals[4] = {e.x, e.y, e.z, e.w};
    float ov[4];
    #pragma unroll
    for(int e2 = 0; e2 < 4; e2++){
      int dd = (dws[g] >> (e2 * 8)) & 255;
      ov[e2] = vals[e2] + ((dd != 255) ? w8s[wv][dd & 7] : 0.f);
      if(dd == 0) fpart += vals[e2];
    }
    float4 o; o.x = ov[0]; o.y = ov[1]; o.z = ov[2]; o.w = ov[3];
    *(float4*)(abrow + c0 + g * 4) = o;
  }
  float fsum = wsum(fpart);
  if(lane == 0) fvals[widx] = fsum;
}

// ---------------- staging GEMM (32KB LDS): q,k (f32) and v (bf16) = X @ {Wq,Wk,Wv}
__global__ __launch_bounds__(256) void k_proj3(const float* X, const float* Wq, const float* Wk,
                                               const float* Wv, float* qf, float* kf, u16* vb){
  __shared__ float xs[32][256];
  int t = threadIdx.x;
  int proj = blockIdx.x >> 7;
  int rb = blockIdx.x & 127;
  const float* W = (proj == 0) ? Wq : (proj == 1) ? Wk : Wv;
  const float* Xb = X + (size_t)rb * 32 * 256;
  #pragma unroll
  for(int m = 0; m < 32; m++) xs[m][t] = Xb[m * 256 + t];
  __syncthreads();
  float acc[32];
  #pragma unroll
  for(int r = 0; r < 32; r++) acc[r] = 0.f;
  for(int k4 = 0; k4 < 64; k4++){
    float w0 = W[(size_t)(k4 * 4 + 0) * 256 + t];
    float w1 = W[(size_t)(k4 * 4 + 1) * 256 + t];
    float w2 = W[(size_t)(k4 * 4 + 2) * 256 + t];
    float w3 = W[(size_t)(k4 * 4 + 3) * 256 + t];
    #pragma unroll
    for(int r = 0; r < 32; r++){
      float4 xv = *(const float4*)&xs[r][k4 * 4];
      acc[r] = fmaf(xv.x, w0, fmaf(xv.y, w1, fmaf(xv.z, w2, fmaf(xv.w, w3, acc[r]))));
    }
  }
  int rowbase = rb * 32;
  if(proj == 2){
    for(int r = 0; r < 32; r++) vb[(size_t)(rowbase + r) * 256 + t] = f2b(acc[r]);
  } else {
    float* dst = (proj == 0) ? qf : kf;
    for(int r = 0; r < 32; r++) dst[(size_t)(rowbase + r) * 256 + t] = acc[r];
  }
}

// ---------------- fused attention + out-projection: TWO-PASS softmax (LDS score buffer)
// Identical to the R12-passing body except the online update is split into
// pass1 (scores -> sc[], no loop-carried dep) + pass2 (max, exp-sum, PV).
__global__ __launch_bounds__(256) void k_fusedattn(
    const float* x, const int* adj, const float* ea,
    const float* qf, const float* kf, const u16* vb,
    const float* Wo, const float* Wf, float* x2)
{
  __shared__ float qs[256];
  __shared__ float aos[256];
  __shared__ float fs[8];
  __shared__ u16 nlist[1024];
  __shared__ float sc[4][64];
  __shared__ int ncnt_s;
  int t = threadIdx.x, wv = t >> 6, lane = t & 63;
  int bi = blockIdx.x, b = bi >> 10, i = bi & 1023;
  const int* arow = adj + (size_t)bi * 1024;
  qs[t] = qf[(size_t)bi * 256 + t];
  if(wv == 0){
    int base = 0;
    for(int it = 0; it < 16; it++){
      int j = it * 64 + lane;
      int a = (arow[j] != 0) ? 1 : 0;
      int inc = a;
      #pragma unroll
      for(int off = 1; off < 64; off <<= 1){ int u = __shfl_up(inc, off, 64); if(lane >= off) inc += u; }
      if(a) nlist[base + inc - 1] = (u16)j;
      base += __shfl(inc, 63, 64);
    }
    if(lane == 0) ncnt_s = base;
  }
  __syncthreads();
  int cnt = ncnt_s;
  const float scale = 0.17677669529663687f;   // 1/sqrt(32)
  int d = lane & 31;
  bool isV = (lane >= 32);
  #pragma unroll
  for(int hh = 0; hh < 2; hh++){
    int h = wv * 2 + hh;
    const float* Kb = kf + ((size_t)(b << 10)) * 256 + h * 32 + d;
    const u16*   Vb = vb + ((size_t)(b << 10)) * 256 + h * 32 + d;
    const float* erow = ea + ((((size_t)((b << 3) + h)) << 10) + (size_t)i) * 1024;
    float q_d = qs[h * 32 + d];
    float S = 0.f, o = 0.f, fp = 0.f;
    if(cnt > 0 && cnt <= 64){
      // ---- pass 1: scores (independent iterations -> loads pipeline)
      for(int idx = 0; idx < cnt; idx++){
        int j = nlist[idx];
        float kv = isV ? 0.f : Kb[(size_t)j * 256];
        float prod = isV ? 0.f : kv * q_d;
        #pragma unroll
        for(int off = 16; off >= 1; off >>= 1) prod += __shfl_xor(prod, off, 64);
        float e = erow[j];
        float s = __shfl(prod, 0, 64) * scale + e;
        if(lane == 0) sc[wv][idx] = s;
        fp += e;
      }
      __builtin_amdgcn_wave_barrier();           // LDS visibility within the wave
      // ---- pass 2: exact max, exp-sum, PV (only VALU-latency carried deps)
      float m = -3.0e38f;
      for(int idx = 0; idx < cnt; idx++) m = fmaxf(m, sc[wv][idx]);
      for(int idx = 0; idx < cnt; idx++){
        int j = nlist[idx];
        float p = __expf(sc[wv][idx] - m);
        S += p;
        if(isV) o = fmaf(p, b2f(Vb[(size_t)j * 256]), o);
      }
    } else if(cnt > 64){
      // ---- fallback: R9-verbatim online softmax (never hit at 2% density)
      float m = -3.0e38f;
      for(int idx = 0; idx < cnt; idx++){
        int j = nlist[idx];
        float kv = isV ? b2f(Vb[(size_t)j * 256]) : Kb[(size_t)j * 256];
        float prod = isV ? 0.f : kv * q_d;
        #pragma unroll
        for(int off = 16; off >= 1; off >>= 1) prod += __shfl_xor(prod, off, 64);
        float e = erow[j];
        float s = __shfl(prod, 0, 64) * scale + e;
        float nm = fmaxf(m, s);
        float rs = __expf(m - nm);
        float p  = __expf(s - nm);
        S = S * rs + p;
        o = o * rs + p * (isV ? kv : 0.f);
        m = nm;
        fp += e;
      }
    } else {
      // zero-degree: softmax over all -1e9 == uniform -> mean of V; f = 0
      S = 1024.f;
      for(int j = 0; j < 1024; j++) o += (isV ? b2f(Vb[(size_t)j * 256]) : 0.f);
    }
    if(isV) aos[h * 32 + d] = o / S;
    if(lane == 0) fs[h] = fp / fmaxf((float)cnt, 1.f);
  }
  __syncthreads();
  float res = x[(size_t)bi * 256 + t];
  for(int k = 0; k < 256; k++) res = fmaf(aos[k], Wo[(size_t)k * 256 + t], res);
  #pragma unroll
  for(int h = 0; h < 8; h++) res = fmaf(fs[h], Wf[(size_t)h * 256 + t], res);
  x2[(size_t)bi * 256 + t] = res;
}

extern "C" void kernel_launch(void* const* d_in, const int* in_sizes, int n_in,
                              void* d_out, int out_size, void* d_ws, size_t ws_size,
                              hipStream_t stream) {
  float* out = (float*)d_out;
  float* x2   = out;                 // [4,1024,256]    f32
  float* ab   = out + 1048576;       // [4,8,1024,1024] f32
  float* expl = out + 34603008;      // [4,1024,1024]   f32 (1.0/0.0)

  bool ok = (n_in == 9) &&
            in_sizes[0] == 1048576  &&
            in_sizes[1] == 4194304  &&
            in_sizes[2] == 33554432 &&
            in_sizes[3] == 65536 && in_sizes[4] == 65536 &&
            in_sizes[5] == 65536 && in_sizes[6] == 65536 &&
            in_sizes[7] == 2048  && in_sizes[8] == 64 &&
            out_size == 38797312;
  if(!ok){
    hipLaunchKernelGGL(k_fill, dim3(4096), dim3(256), 0, stream, x2, 1048576u, 1000.0f);
    return;
  }
  if(ws_size < (size_t)15335424){
    hipLaunchKernelGGL(k_fill, dim3(4096), dim3(256), 0, stream, x2, 1048576u, 2000.0f);
    return;
  }

  const float* x   = (const float*)d_in[0];
  const int*   adj = (const int*)d_in[1];
  const float* ea  = (const float*)d_in[2];
  const float* Wq  = (const float*)d_in[3];
  const float* Wk  = (const float*)d_in[4];
  const float* Wv  = (const float*)d_in[5];
  const float* Wo  = (const float*)d_in[6];
  const float* Wf  = (const float*)d_in[7];
  const float* dw  = (const float*)d_in[8];

  char* ws = (char*)d_ws;
  u64*   bits  = (u64*)(ws + 0);           //  512 KB [0, 524288)
  u8*    dist  = (u8*)(ws + 524288);       //    4 MB [524288, 4718592)
  float* qf    = (float*)(ws + 4718592);   //    4 MB [4718592, 8912896)
  float* kf    = (float*)(ws + 8912896);   //    4 MB [8912896, 13107200)
  u16*   vb    = (u16*)(ws + 13107200);    //    2 MB [13107200, 15204352)
  float* fvals = (float*)(ws + 15204352);  //  128 KB -> 15335424 (written, unused)

  hipLaunchKernelGGL(k_bitset,    dim3(1024), dim3(256), 0, stream, adj, bits);
  hipLaunchKernelGGL(k_bfs,       dim3(4096), dim3(64),  0, stream, bits, dist, expl);
  hipLaunchKernelGGL(k_bias,      dim3(8192), dim3(256), 0, stream, ea, dist, dw, ab, fvals);
  hipLaunchKernelGGL(k_proj3,     dim3(384),  dim3(256), 0, stream, x, Wq, Wk, Wv, qf, kf, vb);
  hipLaunchKernelGGL(k_fusedattn, dim3(4096), dim3(256), 0, stream,
                     x, adj, ea, qf, kf, vb, Wo, Wf, x2);
}

// Round 14
// 421.391 us; speedup vs baseline: 1.0130x; 1.0130x over previous
//
#include <hip/hip_runtime.h>
#include <stdint.h>

#define NN 1024
#define DD 256
#define KHOPS 8

typedef unsigned short u16;
typedef unsigned long long u64;
typedef unsigned char u8;

__device__ __forceinline__ float b2f(u16 u){ return __uint_as_float(((unsigned int)u) << 16); }
__device__ __forceinline__ u16 f2b(float f){
  unsigned int x = __float_as_uint(f);
  unsigned int r = (x + 0x7FFFu + ((x >> 16) & 1u)) >> 16;
  return (u16)r;
}
__device__ __forceinline__ float wsum(float v){
  #pragma unroll
  for(int off = 32; off >= 1; off >>= 1) v += __shfl_xor(v, off, 64);
  return v;
}

// ---------------- sentinel fill (contract-violation signal), f32
__global__ __launch_bounds__(256) void k_fill(float* p, unsigned n, float v){
  unsigned idx = blockIdx.x * 256 + threadIdx.x;
  if(idx < n) p[idx] = v;
}

// ---------------- adjacency int32 -> bitset
__global__ __launch_bounds__(256) void k_bitset(const int* adj, u64* bits){
  int row = blockIdx.x * 4 + (threadIdx.x >> 6);
  int lane = threadIdx.x & 63;
  const int* ar = adj + (size_t)row * NN;
  #pragma unroll
  for(int w = 0; w < 16; w++){
    u64 msk = __ballot(ar[w * 64 + lane] != 0);
    if(lane == 0) bits[(size_t)row * 16 + w] = msk;
  }
}

// ---------------- frontier BFS, register-resident, shfl-butterfly frontier OR
__global__ __launch_bounds__(64) void k_bfs(const u64* bits, u8* dist, float* expl){
  int row = blockIdx.x;                 // b*N + i
  int b = row >> 10;
  int lane = threadIdx.x;
  __shared__ __attribute__((aligned(16))) u8 drow[NN];
  const u64* bb = bits + ((size_t)(b << 10)) * 16;
  const u64* myrow = bits + (size_t)row * 16;
  u64 vis[16], cur[16];
  #pragma unroll
  for(int w = 0; w < 16; w++){ u64 v = myrow[w]; vis[w] = v; cur[w] = v; }
  { int4 ff; ff.x = ff.y = ff.z = ff.w = -1; ((int4*)drow)[lane] = ff; }
  __syncthreads();
  #pragma unroll
  for(int it = 0; it < 16; it++)
    if((cur[it] >> lane) & 1) drow[it * 64 + lane] = 0;
  for(int k = 1; k < KHOPS; k++){
    u64 acc[16];
    #pragma unroll
    for(int w = 0; w < 16; w++) acc[w] = 0;
    #pragma unroll
    for(int it = 0; it < 16; it++){
      if((cur[it] >> lane) & 1){
        const u64* r = bb + (size_t)(it * 64 + lane) * 16;
        #pragma unroll
        for(int w = 0; w < 16; w++) acc[w] |= r[w];
      }
    }
    #pragma unroll
    for(int mask = 32; mask >= 1; mask >>= 1){
      #pragma unroll
      for(int w = 0; w < 16; w++) acc[w] |= __shfl_xor(acc[w], mask, 64);
    }
    u64 any = 0;
    #pragma unroll
    for(int w = 0; w < 16; w++){
      u64 nw = acc[w] & ~vis[w];
      vis[w] |= nw;
      cur[w] = nw;
      any |= nw;
    }
    if(any == 0) break;                          // wave-uniform
    #pragma unroll
    for(int it = 0; it < 16; it++)
      if((cur[it] >> lane) & 1) drow[it * 64 + lane] = (u8)k;
  }
  __syncthreads();
  ((int4*)(dist + (size_t)row * NN))[lane] = ((const int4*)drow)[lane];
  float* eo = expl + (size_t)row * NN;
  #pragma unroll
  for(int it = 0; it < 16; it++){
    int j = it * 64 + lane;
    eo[j] = ((vis[it] >> lane) & 1) ? 1.0f : 0.0f;
  }
}

// ---------------- att_bias = ea + weight[dist] (f32) + fusion numerators fvals (f32, exact)
__global__ __launch_bounds__(256) void k_bias(const float* ea, const u8* dist, const float* dw,
                                              float* ab_out, float* fvals){
  __shared__ float w8s[4][8];
  int wv = threadIdx.x >> 6, lane = threadIdx.x & 63;
  int widx = blockIdx.x * 4 + wv;
  int i = widx & 1023, b = widx >> 13;
  int h = (widx >> 10) & 7;
  int bn_i = (b << 10) + i;
  if(lane < 8) w8s[wv][lane] = dw[lane * 8 + h];
  __syncthreads();
  const float* earow = ea + (size_t)widx * NN;
  const u8* drow = dist + (size_t)bn_i * NN;
  float* abrow = ab_out + (size_t)widx * NN;
  int c0 = lane << 4;
  int4 d4 = *(const int4*)(drow + c0);
  unsigned dws[4] = {(unsigned)d4.x,(unsigned)d4.y,(unsigned)d4.z,(unsigned)d4.w};
  float fpart = 0.f;
  #pragma unroll
  for(int g = 0; g < 4; g++){
    float4 e = *(const float4*)(earow + c0 + g * 4);
    float vals[4] = {e.x, e.y, e.z, e.w};
    float ov[4];
    #pragma unroll
    for(int e2 = 0; e2 < 4; e2++){
      int dd = (dws[g] >> (e2 * 8)) & 255;
      ov[e2] = vals[e2] + ((dd != 255) ? w8s[wv][dd & 7] : 0.f);
      if(dd == 0) fpart += vals[e2];
    }
    float4 o; o.x = ov[0]; o.y = ov[1]; o.z = ov[2]; o.w = ov[3];
    *(float4*)(abrow + c0 + g * 4) = o;
  }
  float fsum = wsum(fpart);
  if(lane == 0) fvals[widx] = fsum;
}

// ---------------- staging GEMM (32KB LDS): q,k (f32) and v (bf16) = X @ {Wq,Wk,Wv}
__global__ __launch_bounds__(256) void k_proj3(const float* X, const float* Wq, const float* Wk,
                                               const float* Wv, float* qf, float* kf, u16* vb){
  __shared__ float xs[32][256];
  int t = threadIdx.x;
  int proj = blockIdx.x >> 7;
  int rb = blockIdx.x & 127;
  const float* W = (proj == 0) ? Wq : (proj == 1) ? Wk : Wv;
  const float* Xb = X + (size_t)rb * 32 * 256;
  #pragma unroll
  for(int m = 0; m < 32; m++) xs[m][t] = Xb[m * 256 + t];
  __syncthreads();
  float acc[32];
  #pragma unroll
  for(int r = 0; r < 32; r++) acc[r] = 0.f;
  for(int k4 = 0; k4 < 64; k4++){
    float w0 = W[(size_t)(k4 * 4 + 0) * 256 + t];
    float w1 = W[(size_t)(k4 * 4 + 1) * 256 + t];
    float w2 = W[(size_t)(k4 * 4 + 2) * 256 + t];
    float w3 = W[(size_t)(k4 * 4 + 3) * 256 + t];
    #pragma unroll
    for(int r = 0; r < 32; r++){
      float4 xv = *(const float4*)&xs[r][k4 * 4];
      acc[r] = fmaf(xv.x, w0, fmaf(xv.y, w1, fmaf(xv.z, w2, fmaf(xv.w, w3, acc[r]))));
    }
  }
  int rowbase = rb * 32;
  if(proj == 2){
    for(int r = 0; r < 32; r++) vb[(size_t)(rowbase + r) * 256 + t] = f2b(acc[r]);
  } else {
    float* dst = (proj == 0) ? qf : kf;
    for(int r = 0; r < 32; r++) dst[(size_t)(rowbase + r) * 256 + t] = acc[r];
  }
}

// ---------------- fused attention + out-projection: two-pass softmax,
// pass1 unrolled x4 (4 gathers in flight), pass2 x2, 4-acc epilogue.
__global__ __launch_bounds__(256) void k_fusedattn(
    const float* x, const int* adj, const float* ea,
    const float* qf, const float* kf, const u16* vb,
    const float* Wo, const float* Wf, float* x2)
{
  __shared__ float qs[256];
  __shared__ float aos[256];
  __shared__ float fs[8];
  __shared__ u16 nlist[1024];
  __shared__ float sc[4][64];
  __shared__ int ncnt_s;
  int t = threadIdx.x, wv = t >> 6, lane = t & 63;
  int bi = blockIdx.x, b = bi >> 10, i = bi & 1023;
  const int* arow = adj + (size_t)bi * 1024;
  qs[t] = qf[(size_t)bi * 256 + t];
  if(wv == 0){
    int base = 0;
    for(int it = 0; it < 16; it++){
      int j = it * 64 + lane;
      int a = (arow[j] != 0) ? 1 : 0;
      int inc = a;
      #pragma unroll
      for(int off = 1; off < 64; off <<= 1){ int u = __shfl_up(inc, off, 64); if(lane >= off) inc += u; }
      if(a) nlist[base + inc - 1] = (u16)j;
      base += __shfl(inc, 63, 64);
    }
    if(lane == 0) ncnt_s = base;
  }
  __syncthreads();
  int cnt = ncnt_s;
  const float scale = 0.17677669529663687f;   // 1/sqrt(32)
  int d = lane & 31;
  bool isV = (lane >= 32);
  #pragma unroll
  for(int hh = 0; hh < 2; hh++){
    int h = wv * 2 + hh;
    const float* Kb = kf + ((size_t)(b << 10)) * 256 + h * 32 + d;
    const u16*   Vb = vb + ((size_t)(b << 10)) * 256 + h * 32 + d;
    const float* erow = ea + ((((size_t)((b << 3) + h)) << 10) + (size_t)i) * 1024;
    float q_d = qs[h * 32 + d];
    float S = 0.f, o = 0.f, fp = 0.f;
    if(cnt > 0 && cnt <= 64){
      // ---- pass 1: scores, unrolled x4 (independent gathers pipeline)
      for(int idx = 0; idx < cnt; idx += 4){
        int i1 = (idx + 1 < cnt) ? idx + 1 : cnt - 1;
        int i2 = (idx + 2 < cnt) ? idx + 2 : cnt - 1;
        int i3 = (idx + 3 < cnt) ? idx + 3 : cnt - 1;
        int j0 = nlist[idx], j1 = nlist[i1], j2 = nlist[i2], j3 = nlist[i3];
        float e0 = erow[j0], e1 = erow[j1], e2 = erow[j2], e3 = erow[j3];
        float p0 = isV ? 0.f : Kb[(size_t)j0 * 256] * q_d;
        float p1 = isV ? 0.f : Kb[(size_t)j1 * 256] * q_d;
        float p2 = isV ? 0.f : Kb[(size_t)j2 * 256] * q_d;
        float p3 = isV ? 0.f : Kb[(size_t)j3 * 256] * q_d;
        #pragma unroll
        for(int off = 16; off >= 1; off >>= 1){
          p0 += __shfl_xor(p0, off, 64);
          p1 += __shfl_xor(p1, off, 64);
          p2 += __shfl_xor(p2, off, 64);
          p3 += __shfl_xor(p3, off, 64);
        }
        float s0 = __shfl(p0, 0, 64) * scale + e0;
        float s1 = __shfl(p1, 0, 64) * scale + e1;
        float s2 = __shfl(p2, 0, 64) * scale + e2;
        float s3 = __shfl(p3, 0, 64) * scale + e3;
        if(lane == 0){
          sc[wv][idx] = s0; sc[wv][i1] = s1; sc[wv][i2] = s2; sc[wv][i3] = s3;
        }
        fp += e0;
        if(idx + 1 < cnt) fp += e1;
        if(idx + 2 < cnt) fp += e2;
        if(idx + 3 < cnt) fp += e3;
      }
      __builtin_amdgcn_wave_barrier();           // LDS visibility within the wave
      // ---- pass 2: exact max, exp-sum, PV (unrolled x2)
      float m = -3.0e38f;
      for(int idx = 0; idx < cnt; idx++) m = fmaxf(m, sc[wv][idx]);
      for(int idx = 0; idx < cnt; idx += 2){
        int i1 = (idx + 1 < cnt) ? idx + 1 : cnt - 1;
        int j0 = nlist[idx], j1 = nlist[i1];
        float v0 = isV ? b2f(Vb[(size_t)j0 * 256]) : 0.f;
        float v1 = isV ? b2f(Vb[(size_t)j1 * 256]) : 0.f;
        float q0 = __expf(sc[wv][idx] - m);
        float q1 = __expf(sc[wv][i1] - m);
        S += q0;
        o = fmaf(q0, v0, o);
        if(idx + 1 < cnt){ S += q1; o = fmaf(q1, v1, o); }
      }
    } else if(cnt > 64){
      // ---- fallback: R9-verbatim online softmax (never hit at 2% density)
      float m = -3.0e38f;
      for(int idx = 0; idx < cnt; idx++){
        int j = nlist[idx];
        float kv = isV ? b2f(Vb[(size_t)j * 256]) : Kb[(size_t)j * 256];
        float prod = isV ? 0.f : kv * q_d;
        #pragma unroll
        for(int off = 16; off >= 1; off >>= 1) prod += __shfl_xor(prod, off, 64);
        float e = erow[j];
        float s = __shfl(prod, 0, 64) * scale + e;
        float nm = fmaxf(m, s);
        float rs = __expf(m - nm);
        float p  = __expf(s - nm);
        S = S * rs + p;
        o = o * rs + p * (isV ? kv : 0.f);
        m = nm;
        fp += e;
      }
    } else {
      // zero-degree: softmax over all -1e9 == uniform -> mean of V; f = 0
      S = 1024.f;
      for(int j = 0; j < 1024; j++) o += (isV ? b2f(Vb[(size_t)j * 256]) : 0.f);
    }
    if(isV) aos[h * 32 + d] = o / S;
    if(lane == 0) fs[h] = fp / fmaxf((float)cnt, 1.f);
  }
  __syncthreads();
  // ---- epilogue: x + aos@Wo + fs@Wf with 4 independent accumulators
  const float* Wcol = Wo + t;
  float r0 = x[(size_t)bi * 256 + t], r1 = 0.f, r2 = 0.f, r3 = 0.f;
  #pragma unroll 4
  for(int k = 0; k < 256; k += 4){
    r0 = fmaf(aos[k],     Wcol[(size_t)k * 256],       r0);
    r1 = fmaf(aos[k + 1], Wcol[(size_t)(k + 1) * 256], r1);
    r2 = fmaf(aos[k + 2], Wcol[(size_t)(k + 2) * 256], r2);
    r3 = fmaf(aos[k + 3], Wcol[(size_t)(k + 3) * 256], r3);
  }
  float res = (r0 + r1) + (r2 + r3);
  #pragma unroll
  for(int h = 0; h < 8; h++) res = fmaf(fs[h], Wf[(size_t)h * 256 + t], res);
  x2[(size_t)bi * 256 + t] = res;
}

extern "C" void kernel_launch(void* const* d_in, const int* in_sizes, int n_in,
                              void* d_out, int out_size, void* d_ws, size_t ws_size,
                              hipStream_t stream) {
  float* out = (float*)d_out;
  float* x2   = out;                 // [4,1024,256]    f32
  float* ab   = out + 1048576;       // [4,8,1024,1024] f32
  float* expl = out + 34603008;      // [4,1024,1024]   f32 (1.0/0.0)

  bool ok = (n_in == 9) &&
            in_sizes[0] == 1048576  &&
            in_sizes[1] == 4194304  &&
            in_sizes[2] == 33554432 &&
            in_sizes[3] == 65536 && in_sizes[4] == 65536 &&
            in_sizes[5] == 65536 && in_sizes[6] == 65536 &&
            in_sizes[7] == 2048  && in_sizes[8] == 64 &&
            out_size == 38797312;
  if(!ok){
    hipLaunchKernelGGL(k_fill, dim3(4096), dim3(256), 0, stream, x2, 1048576u, 1000.0f);
    return;
  }
  if(ws_size < (size_t)15335424){
    hipLaunchKernelGGL(k_fill, dim3(4096), dim3(256), 0, stream, x2, 1048576u, 2000.0f);
    return;
  }

  const float* x   = (const float*)d_in[0];
  const int*   adj = (const int*)d_in[1];
  const float* ea  = (const float*)d_in[2];
  const float* Wq  = (const float*)d_in[3];
  const float* Wk  = (const float*)d_in[4];
  const float* Wv  = (const float*)d_in[5];
  const float* Wo  = (const float*)d_in[6];
  const float* Wf  = (const float*)d_in[7];
  const float* dw  = (const float*)d_in[8];

  char* ws = (char*)d_ws;
  u64*   bits  = (u64*)(ws + 0);           //  512 KB [0, 524288)
  u8*    dist  = (u8*)(ws + 524288);       //    4 MB [524288, 4718592)
  float* qf    = (float*)(ws + 4718592);   //    4 MB [4718592, 8912896)
  float* kf    = (float*)(ws + 8912896);   //    4 MB [8912896, 13107200)
  u16*   vb    = (u16*)(ws + 13107200);    //    2 MB [13107200, 15204352)
  float* fvals = (float*)(ws + 15204352);  //  128 KB -> 15335424 (written, unused)

  hipLaunchKernelGGL(k_bitset,    dim3(1024), dim3(256), 0, stream, adj, bits);
  hipLaunchKernelGGL(k_bfs,       dim3(4096), dim3(64),  0, stream, bits, dist, expl);
  hipLaunchKernelGGL(k_bias,      dim3(8192), dim3(256), 0, stream, ea, dist, dw, ab, fvals);
  hipLaunchKernelGGL(k_proj3,     dim3(384),  dim3(256), 0, stream, x, Wq, Wk, Wv, qf, kf, vb);
  hipLaunchKernelGGL(k_fusedattn, dim3(4096), dim3(256), 0, stream,
                     x, adj, ea, qf, kf, vb, Wo, Wf, x2);
}

// Round 15
// 379.006 us; speedup vs baseline: 1.1262x; 1.1118x over previous
//
#include <hip/hip_runtime.h>
#include <stdint.h>

#define NN 1024
#define DD 256
#define KHOPS 8

typedef unsigned short u16;
typedef unsigned long long u64;
typedef unsigned char u8;

__device__ __forceinline__ float b2f(u16 u){ return __uint_as_float(((unsigned int)u) << 16); }
__device__ __forceinline__ u16 f2b(float f){
  unsigned int x = __float_as_uint(f);
  unsigned int r = (x + 0x7FFFu + ((x >> 16) & 1u)) >> 16;
  return (u16)r;
}
__device__ __forceinline__ float wsum(float v){
  #pragma unroll
  for(int off = 32; off >= 1; off >>= 1) v += __shfl_xor(v, off, 64);
  return v;
}

// ---------------- sentinel fill (contract-violation signal), f32
__global__ __launch_bounds__(256) void k_fill(float* p, unsigned n, float v){
  unsigned idx = blockIdx.x * 256 + threadIdx.x;
  if(idx < n) p[idx] = v;
}

// ---------------- adjacency int32 -> bitset
__global__ __launch_bounds__(256) void k_bitset(const int* adj, u64* bits){
  int row = blockIdx.x * 4 + (threadIdx.x >> 6);
  int lane = threadIdx.x & 63;
  const int* ar = adj + (size_t)row * NN;
  #pragma unroll
  for(int w = 0; w < 16; w++){
    u64 msk = __ballot(ar[w * 64 + lane] != 0);
    if(lane == 0) bits[(size_t)row * 16 + w] = msk;
  }
}

// ---------------- frontier BFS, register-resident, shfl-butterfly frontier OR
__global__ __launch_bounds__(64) void k_bfs(const u64* bits, u8* dist, float* expl){
  int row = blockIdx.x;                 // b*N + i
  int b = row >> 10;
  int lane = threadIdx.x;
  __shared__ __attribute__((aligned(16))) u8 drow[NN];
  const u64* bb = bits + ((size_t)(b << 10)) * 16;
  const u64* myrow = bits + (size_t)row * 16;
  u64 vis[16], cur[16];
  #pragma unroll
  for(int w = 0; w < 16; w++){ u64 v = myrow[w]; vis[w] = v; cur[w] = v; }
  { int4 ff; ff.x = ff.y = ff.z = ff.w = -1; ((int4*)drow)[lane] = ff; }
  __syncthreads();
  #pragma unroll
  for(int it = 0; it < 16; it++)
    if((cur[it] >> lane) & 1) drow[it * 64 + lane] = 0;
  for(int k = 1; k < KHOPS; k++){
    u64 acc[16];
    #pragma unroll
    for(int w = 0; w < 16; w++) acc[w] = 0;
    #pragma unroll
    for(int it = 0; it < 16; it++){
      if((cur[it] >> lane) & 1){
        const u64* r = bb + (size_t)(it * 64 + lane) * 16;
        #pragma unroll
        for(int w = 0; w < 16; w++) acc[w] |= r[w];
      }
    }
    #pragma unroll
    for(int mask = 32; mask >= 1; mask >>= 1){
      #pragma unroll
      for(int w = 0; w < 16; w++) acc[w] |= __shfl_xor(acc[w], mask, 64);
    }
    u64 any = 0;
    #pragma unroll
    for(int w = 0; w < 16; w++){
      u64 nw = acc[w] & ~vis[w];
      vis[w] |= nw;
      cur[w] = nw;
      any |= nw;
    }
    if(any == 0) break;                          // wave-uniform
    #pragma unroll
    for(int it = 0; it < 16; it++)
      if((cur[it] >> lane) & 1) drow[it * 64 + lane] = (u8)k;
  }
  __syncthreads();
  ((int4*)(dist + (size_t)row * NN))[lane] = ((const int4*)drow)[lane];
  float* eo = expl + (size_t)row * NN;
  #pragma unroll
  for(int it = 0; it < 16; it++){
    int j = it * 64 + lane;
    eo[j] = ((vis[it] >> lane) & 1) ? 1.0f : 0.0f;
  }
}

// ---------------- att_bias = ea + weight[dist] (f32) + fusion numerators fvals (f32, exact)
__global__ __launch_bounds__(256) void k_bias(const float* ea, const u8* dist, const float* dw,
                                              float* ab_out, float* fvals){
  __shared__ float w8s[4][8];
  int wv = threadIdx.x >> 6, lane = threadIdx.x & 63;
  int widx = blockIdx.x * 4 + wv;
  int i = widx & 1023, b = widx >> 13;
  int h = (widx >> 10) & 7;
  int bn_i = (b << 10) + i;
  if(lane < 8) w8s[wv][lane] = dw[lane * 8 + h];
  __syncthreads();
  const float* earow = ea + (size_t)widx * NN;
  const u8* drow = dist + (size_t)bn_i * NN;
  float* abrow = ab_out + (size_t)widx * NN;
  int c0 = lane << 4;
  int4 d4 = *(const int4*)(drow + c0);
  unsigned dws[4] = {(unsigned)d4.x,(unsigned)d4.y,(unsigned)d4.z,(unsigned)d4.w};
  float fpart = 0.f;
  #pragma unroll
  for(int g = 0; g < 4; g++){
    float4 e = *(const float4*)(earow + c0 + g * 4);
    float vals[4] = {e.x, e.y, e.z, e.w};
    float ov[4];
    #pragma unroll
    for(int e2 = 0; e2 < 4; e2++){
      int dd = (dws[g] >> (e2 * 8)) & 255;
      ov[e2] = vals[e2] + ((dd != 255) ? w8s[wv][dd & 7] : 0.f);
      if(dd == 0) fpart += vals[e2];
    }
    float4 o; o.x = ov[0]; o.y = ov[1]; o.z = ov[2]; o.w = ov[3];
    *(float4*)(abrow + c0 + g * 4) = o;
  }
  float fsum = wsum(fpart);
  if(lane == 0) fvals[widx] = fsum;
}

// ---------------- staging GEMM (32KB LDS): q,k (f32) and v (bf16) = X @ {Wq,Wk,Wv}
__global__ __launch_bounds__(256) void k_proj3(const float* X, const float* Wq, const float* Wk,
                                               const float* Wv, float* qf, float* kf, u16* vb){
  __shared__ float xs[32][256];
  int t = threadIdx.x;
  int proj = blockIdx.x >> 7;
  int rb = blockIdx.x & 127;
  const float* W = (proj == 0) ? Wq : (proj == 1) ? Wk : Wv;
  const float* Xb = X + (size_t)rb * 32 * 256;
  #pragma unroll
  for(int m = 0; m < 32; m++) xs[m][t] = Xb[m * 256 + t];
  __syncthreads();
  float acc[32];
  #pragma unroll
  for(int r = 0; r < 32; r++) acc[r] = 0.f;
  for(int k4 = 0; k4 < 64; k4++){
    float w0 = W[(size_t)(k4 * 4 + 0) * 256 + t];
    float w1 = W[(size_t)(k4 * 4 + 1) * 256 + t];
    float w2 = W[(size_t)(k4 * 4 + 2) * 256 + t];
    float w3 = W[(size_t)(k4 * 4 + 3) * 256 + t];
    #pragma unroll
    for(int r = 0; r < 32; r++){
      float4 xv = *(const float4*)&xs[r][k4 * 4];
      acc[r] = fmaf(xv.x, w0, fmaf(xv.y, w1, fmaf(xv.z, w2, fmaf(xv.w, w3, acc[r]))));
    }
  }
  int rowbase = rb * 32;
  if(proj == 2){
    for(int r = 0; r < 32; r++) vb[(size_t)(rowbase + r) * 256 + t] = f2b(acc[r]);
  } else {
    float* dst = (proj == 0) ? qf : kf;
    for(int r = 0; r < 32; r++) dst[(size_t)(rowbase + r) * 256 + t] = acc[r];
  }
}

// ---------------- fused attention + out-projection: shuffle-lean version.
// nlist via ballot+ctz; e-values prefetched in one gather; pair-scores with
// half-wave butterflies; softmax recomputed per-lane from LDS (no broadcasts).
__global__ __launch_bounds__(256) void k_fusedattn(
    const float* x, const int* adj, const float* ea,
    const float* qf, const float* kf, const u16* vb,
    const float* Wo, const float* Wf, float* x2)
{
  __shared__ float qs[256];
  __shared__ float aos[256];
  __shared__ float fs[8];
  __shared__ u16 nlist[1024];
  __shared__ float sc[4][64];
  __shared__ float evl[4][64];
  __shared__ u64 wm[16];
  __shared__ int bs[16];
  __shared__ int ncnt_s;
  int t = threadIdx.x, wv = t >> 6, lane = t & 63;
  int bi = blockIdx.x, b = bi >> 10, i = bi & 1023;
  const int* arow = adj + (size_t)bi * 1024;
  qs[t] = qf[(size_t)bi * 256 + t];
  if(wv == 0){
    // ballots -> word masks + popcount prefix (lane 0), then ctz expansion (lanes 0-15)
    int run = 0;
    for(int it = 0; it < 16; it++){
      u64 w = __ballot(arow[it * 64 + lane] != 0);
      if(lane == 0){ wm[it] = w; bs[it] = run; run += __popcll(w); }
    }
    if(lane == 0) ncnt_s = run;
    __builtin_amdgcn_wave_barrier();
    if(lane < 16){
      u64 w = wm[lane];
      int pos = bs[lane];
      while(w){
        int bpos = __builtin_ctzll(w);
        nlist[pos++] = (u16)(lane * 64 + bpos);
        w &= w - 1;
      }
    }
  }
  __syncthreads();
  int cnt = ncnt_s;
  const float scale = 0.17677669529663687f;   // 1/sqrt(32)
  int d = lane & 31;
  int half = lane >> 5;
  bool isV = (lane >= 32);
  #pragma unroll
  for(int hh = 0; hh < 2; hh++){
    int h = wv * 2 + hh;
    int widx = (((b << 3) + h) << 10) + i;
    const float* Kb = kf + ((size_t)(b << 10)) * 256 + h * 32 + d;
    const u16*   Vb = vb + ((size_t)(b << 10)) * 256 + h * 32 + d;
    float q_d = qs[h * 32 + d];
    float S = 0.f, o = 0.f, fp = 0.f;
    if(cnt > 0 && cnt <= 64){
      // ---- e-prefetch: all gathers in one instruction
      for(int s = lane; s < cnt; s += 64)
        evl[wv][s] = ea[(size_t)widx * 1024 + nlist[s]];
      __builtin_amdgcn_wave_barrier();
      // ---- pair scores: half 0 -> slot u, half 1 -> slot u+1; 5-step butterfly
      for(int u = 0; u < cnt; u += 2){
        int s = u + half;
        bool valid = (s < cnt);
        int j = nlist[valid ? s : u];
        float prod = Kb[(size_t)j * 256] * q_d;
        #pragma unroll
        for(int off = 16; off >= 1; off >>= 1) prod += __shfl_xor(prod, off, 64);
        if((lane & 31) == 0 && valid)
          sc[wv][s] = prod * scale + evl[wv][s];
      }
      __builtin_amdgcn_wave_barrier();
      // ---- softmax per-lane from LDS (no cross-lane broadcasts)
      float m = -3.0e38f;
      for(int s = 0; s < cnt; s++) m = fmaxf(m, sc[wv][s]);
      for(int s = 0; s < cnt; s++) fp += evl[wv][s];
      for(int s = half; s < cnt; s += 2){
        float p = __expf(sc[wv][s] - m);
        S += p;
        o = fmaf(p, b2f(Vb[(size_t)nlist[s] * 256]), o);
      }
      o += __shfl_xor(o, 32, 64);
      S += __shfl_xor(S, 32, 64);
      if(lane < 32) aos[h * 32 + d] = o / S;
      if(lane == 0) fs[h] = fp / (float)cnt;
    } else if(cnt > 64){
      // ---- fallback: R12-verbatim online softmax (never hit at 2% density)
      float m = -3.0e38f;
      for(int idx = 0; idx < cnt; idx++){
        int j = nlist[idx];
        float kv = isV ? b2f(Vb[(size_t)j * 256]) : Kb[(size_t)j * 256];
        float prod = isV ? 0.f : kv * q_d;
        #pragma unroll
        for(int off = 16; off >= 1; off >>= 1) prod += __shfl_xor(prod, off, 64);
        float e = ea[(size_t)widx * 1024 + j];
        float s = __shfl(prod, 0, 64) * scale + e;
        float nm = fmaxf(m, s);
        float rs = __expf(m - nm);
        float p  = __expf(s - nm);
        S = S * rs + p;
        o = o * rs + p * (isV ? kv : 0.f);
        m = nm;
        fp += e;
      }
      if(isV) aos[h * 32 + d] = o / S;
      if(lane == 0) fs[h] = fp / (float)cnt;
    } else {
      // zero-degree: softmax over all -1e9 == uniform -> mean of V; f = 0
      S = 1024.f;
      for(int j2 = half; j2 < 1024; j2 += 2)
        o += b2f(Vb[(size_t)j2 * 256]);
      o += __shfl_xor(o, 32, 64);
      if(lane < 32) aos[h * 32 + d] = o / S;
      if(lane == 0) fs[h] = 0.f;
    }
  }
  __syncthreads();
  // ---- epilogue: x + aos@Wo + fs@Wf with 4 independent accumulators
  const float* Wcol = Wo + t;
  float r0 = x[(size_t)bi * 256 + t], r1 = 0.f, r2 = 0.f, r3 = 0.f;
  #pragma unroll 4
  for(int k = 0; k < 256; k += 4){
    r0 = fmaf(aos[k],     Wcol[(size_t)k * 256],       r0);
    r1 = fmaf(aos[k + 1], Wcol[(size_t)(k + 1) * 256], r1);
    r2 = fmaf(aos[k + 2], Wcol[(size_t)(k + 2) * 256], r2);
    r3 = fmaf(aos[k + 3], Wcol[(size_t)(k + 3) * 256], r3);
  }
  float res = (r0 + r1) + (r2 + r3);
  #pragma unroll
  for(int h = 0; h < 8; h++) res = fmaf(fs[h], Wf[(size_t)h * 256 + t], res);
  x2[(size_t)bi * 256 + t] = res;
}

extern "C" void kernel_launch(void* const* d_in, const int* in_sizes, int n_in,
                              void* d_out, int out_size, void* d_ws, size_t ws_size,
                              hipStream_t stream) {
  float* out = (float*)d_out;
  float* x2   = out;                 // [4,1024,256]    f32
  float* ab   = out + 1048576;       // [4,8,1024,1024] f32
  float* expl = out + 34603008;      // [4,1024,1024]   f32 (1.0/0.0)

  bool ok = (n_in == 9) &&
            in_sizes[0] == 1048576  &&
            in_sizes[1] == 4194304  &&
            in_sizes[2] == 33554432 &&
            in_sizes[3] == 65536 && in_sizes[4] == 65536 &&
            in_sizes[5] == 65536 && in_sizes[6] == 65536 &&
            in_sizes[7] == 2048  && in_sizes[8] == 64 &&
            out_size == 38797312;
  if(!ok){
    hipLaunchKernelGGL(k_fill, dim3(4096), dim3(256), 0, stream, x2, 1048576u, 1000.0f);
    return;
  }
  if(ws_size < (size_t)15335424){
    hipLaunchKernelGGL(k_fill, dim3(4096), dim3(256), 0, stream, x2, 1048576u, 2000.0f);
    return;
  }

  const float* x   = (const float*)d_in[0];
  const int*   adj = (const int*)d_in[1];
  const float* ea  = (const float*)d_in[2];
  const float* Wq  = (const float*)d_in[3];
  const float* Wk  = (const float*)d_in[4];
  const float* Wv  = (const float*)d_in[5];
  const float* Wo  = (const float*)d_in[6];
  const float* Wf  = (const float*)d_in[7];
  const float* dw  = (const float*)d_in[8];

  char* ws = (char*)d_ws;
  u64*   bits  = (u64*)(ws + 0);           //  512 KB [0, 524288)
  u8*    dist  = (u8*)(ws + 524288);       //    4 MB [524288, 4718592)
  float* qf    = (float*)(ws + 4718592);   //    4 MB [4718592, 8912896)
  float* kf    = (float*)(ws + 8912896);   //    4 MB [8912896, 13107200)
  u16*   vb    = (u16*)(ws + 13107200);    //    2 MB [13107200, 15204352)
  float* fvals = (float*)(ws + 15204352);  //  128 KB -> 15335424 (written, unused)

  hipLaunchKernelGGL(k_bitset,    dim3(1024), dim3(256), 0, stream, adj, bits);
  hipLaunchKernelGGL(k_bfs,       dim3(4096), dim3(64),  0, stream, bits, dist, expl);
  hipLaunchKernelGGL(k_bias,      dim3(8192), dim3(256), 0, stream, ea, dist, dw, ab, fvals);
  hipLaunchKernelGGL(k_proj3,     dim3(384),  dim3(256), 0, stream, x, Wq, Wk, Wv, qf, kf, vb);
  hipLaunchKernelGGL(k_fusedattn, dim3(4096), dim3(256), 0, stream,
                     x, adj, ea, qf, kf, vb, Wo, Wf, x2);
}

// Round 16
// 304.178 us; speedup vs baseline: 1.4033x; 1.2460x over previous
//
#include <hip/hip_runtime.h>
#include <stdint.h>

#define NN 1024
#define DD 256
#define KHOPS 8

typedef unsigned short u16;
typedef unsigned long long u64;
typedef unsigned char u8;

__device__ __forceinline__ float b2f(u16 u){ return __uint_as_float(((unsigned int)u) << 16); }
__device__ __forceinline__ u16 f2b(float f){
  unsigned int x = __float_as_uint(f);
  unsigned int r = (x + 0x7FFFu + ((x >> 16) & 1u)) >> 16;
  return (u16)r;
}
__device__ __forceinline__ float wsum(float v){
  #pragma unroll
  for(int off = 32; off >= 1; off >>= 1) v += __shfl_xor(v, off, 64);
  return v;
}

// ---------------- sentinel fill (contract-violation signal), f32
__global__ __launch_bounds__(256) void k_fill(float* p, unsigned n, float v){
  unsigned idx = blockIdx.x * 256 + threadIdx.x;
  if(idx < n) p[idx] = v;
}

// ---------------- adjacency int32 -> bitset
__global__ __launch_bounds__(256) void k_bitset(const int* adj, u64* bits){
  int row = blockIdx.x * 4 + (threadIdx.x >> 6);
  int lane = threadIdx.x & 63;
  const int* ar = adj + (size_t)row * NN;
  #pragma unroll
  for(int w = 0; w < 16; w++){
    u64 msk = __ballot(ar[w * 64 + lane] != 0);
    if(lane == 0) bits[(size_t)row * 16 + w] = msk;
  }
}

// ---------------- frontier BFS, register-resident, shfl-butterfly frontier OR
__global__ __launch_bounds__(64) void k_bfs(const u64* bits, u8* dist, float* expl){
  int row = blockIdx.x;                 // b*N + i
  int b = row >> 10;
  int lane = threadIdx.x;
  __shared__ __attribute__((aligned(16))) u8 drow[NN];
  const u64* bb = bits + ((size_t)(b << 10)) * 16;
  const u64* myrow = bits + (size_t)row * 16;
  u64 vis[16], cur[16];
  #pragma unroll
  for(int w = 0; w < 16; w++){ u64 v = myrow[w]; vis[w] = v; cur[w] = v; }
  { int4 ff; ff.x = ff.y = ff.z = ff.w = -1; ((int4*)drow)[lane] = ff; }
  __syncthreads();
  #pragma unroll
  for(int it = 0; it < 16; it++)
    if((cur[it] >> lane) & 1) drow[it * 64 + lane] = 0;
  for(int k = 1; k < KHOPS; k++){
    u64 acc[16];
    #pragma unroll
    for(int w = 0; w < 16; w++) acc[w] = 0;
    #pragma unroll
    for(int it = 0; it < 16; it++){
      if((cur[it] >> lane) & 1){
        const u64* r = bb + (size_t)(it * 64 + lane) * 16;
        #pragma unroll
        for(int w = 0; w < 16; w++) acc[w] |= r[w];
      }
    }
    #pragma unroll
    for(int mask = 32; mask >= 1; mask >>= 1){
      #pragma unroll
      for(int w = 0; w < 16; w++) acc[w] |= __shfl_xor(acc[w], mask, 64);
    }
    u64 any = 0;
    #pragma unroll
    for(int w = 0; w < 16; w++){
      u64 nw = acc[w] & ~vis[w];
      vis[w] |= nw;
      cur[w] = nw;
      any |= nw;
    }
    if(any == 0) break;                          // wave-uniform
    #pragma unroll
    for(int it = 0; it < 16; it++)
      if((cur[it] >> lane) & 1) drow[it * 64 + lane] = (u8)k;
  }
  __syncthreads();
  ((int4*)(dist + (size_t)row * NN))[lane] = ((const int4*)drow)[lane];
  float* eo = expl + (size_t)row * NN;
  #pragma unroll
  for(int it = 0; it < 16; it++){
    int j = it * 64 + lane;
    eo[j] = ((vis[it] >> lane) & 1) ? 1.0f : 0.0f;
  }
}

// ---------------- att_bias = ea + weight[dist] (f32) + fusion numerators fvals.
// Per-instruction-contiguous indexing: iteration g covers 1 KB contiguous per wave
// (lane*4 floats), eliminating partial-line write amplification.
__global__ __launch_bounds__(256) void k_bias(const float* ea, const u8* dist, const float* dw,
                                              float* ab_out, float* fvals){
  __shared__ float w8s[4][8];
  int wv = threadIdx.x >> 6, lane = threadIdx.x & 63;
  int widx = blockIdx.x * 4 + wv;
  int i = widx & 1023, b = widx >> 13;
  int h = (widx >> 10) & 7;
  int bn_i = (b << 10) + i;
  if(lane < 8) w8s[wv][lane] = dw[lane * 8 + h];
  __syncthreads();
  const float* earow = ea + (size_t)widx * NN;
  const u8* drow = dist + (size_t)bn_i * NN;
  float* abrow = ab_out + (size_t)widx * NN;
  float fpart = 0.f;
  #pragma unroll
  for(int g = 0; g < 4; g++){
    int idx = g * 256 + lane * 4;              // contiguous 1KB per wave-instruction
    float4 e = *(const float4*)(earow + idx);
    unsigned dd4 = *(const unsigned*)(drow + idx);
    float vals[4] = {e.x, e.y, e.z, e.w};
    float ov[4];
    #pragma unroll
    for(int e2 = 0; e2 < 4; e2++){
      int dd = (dd4 >> (e2 * 8)) & 255;
      ov[e2] = vals[e2] + ((dd != 255) ? w8s[wv][dd & 7] : 0.f);
      if(dd == 0) fpart += vals[e2];
    }
    float4 o; o.x = ov[0]; o.y = ov[1]; o.z = ov[2]; o.w = ov[3];
    *(float4*)(abrow + idx) = o;
  }
  float fsum = wsum(fpart);
  if(lane == 0) fvals[widx] = fsum;
}

// ---------------- staging GEMM (32KB LDS): q,k (f32) and v (bf16) = X @ {Wq,Wk,Wv}
__global__ __launch_bounds__(256) void k_proj3(const float* X, const float* Wq, const float* Wk,
                                               const float* Wv, float* qf, float* kf, u16* vb){
  __shared__ float xs[32][256];
  int t = threadIdx.x;
  int proj = blockIdx.x >> 7;
  int rb = blockIdx.x & 127;
  const float* W = (proj == 0) ? Wq : (proj == 1) ? Wk : Wv;
  const float* Xb = X + (size_t)rb * 32 * 256;
  #pragma unroll
  for(int m = 0; m < 32; m++) xs[m][t] = Xb[m * 256 + t];
  __syncthreads();
  float acc[32];
  #pragma unroll
  for(int r = 0; r < 32; r++) acc[r] = 0.f;
  for(int k4 = 0; k4 < 64; k4++){
    float w0 = W[(size_t)(k4 * 4 + 0) * 256 + t];
    float w1 = W[(size_t)(k4 * 4 + 1) * 256 + t];
    float w2 = W[(size_t)(k4 * 4 + 2) * 256 + t];
    float w3 = W[(size_t)(k4 * 4 + 3) * 256 + t];
    #pragma unroll
    for(int r = 0; r < 32; r++){
      float4 xv = *(const float4*)&xs[r][k4 * 4];
      acc[r] = fmaf(xv.x, w0, fmaf(xv.y, w1, fmaf(xv.z, w2, fmaf(xv.w, w3, acc[r]))));
    }
  }
  int rowbase = rb * 32;
  if(proj == 2){
    for(int r = 0; r < 32; r++) vb[(size_t)(rowbase + r) * 256 + t] = f2b(acc[r]);
  } else {
    float* dst = (proj == 0) ? qf : kf;
    for(int r = 0; r < 32; r++) dst[(size_t)(rowbase + r) * 256 + t] = acc[r];
  }
}

// ---------------- fused attention + out-projection: shuffle-lean version.
// nlist via ballot+ctz; e-values prefetched in one gather; pair-scores with
// half-wave butterflies; softmax recomputed per-lane from LDS (no broadcasts).
__global__ __launch_bounds__(256) void k_fusedattn(
    const float* x, const int* adj, const float* ea,
    const float* qf, const float* kf, const u16* vb,
    const float* Wo, const float* Wf, float* x2)
{
  __shared__ float qs[256];
  __shared__ float aos[256];
  __shared__ float fs[8];
  __shared__ u16 nlist[1024];
  __shared__ float sc[4][64];
  __shared__ float evl[4][64];
  __shared__ u64 wm[16];
  __shared__ int bs[16];
  __shared__ int ncnt_s;
  int t = threadIdx.x, wv = t >> 6, lane = t & 63;
  int bi = blockIdx.x, b = bi >> 10, i = bi & 1023;
  const int* arow = adj + (size_t)bi * 1024;
  qs[t] = qf[(size_t)bi * 256 + t];
  if(wv == 0){
    // ballots -> word masks + popcount prefix (lane 0), then ctz expansion (lanes 0-15)
    int run = 0;
    for(int it = 0; it < 16; it++){
      u64 w = __ballot(arow[it * 64 + lane] != 0);
      if(lane == 0){ wm[it] = w; bs[it] = run; run += __popcll(w); }
    }
    if(lane == 0) ncnt_s = run;
    __builtin_amdgcn_wave_barrier();
    if(lane < 16){
      u64 w = wm[lane];
      int pos = bs[lane];
      while(w){
        int bpos = __builtin_ctzll(w);
        nlist[pos++] = (u16)(lane * 64 + bpos);
        w &= w - 1;
      }
    }
  }
  __syncthreads();
  int cnt = ncnt_s;
  const float scale = 0.17677669529663687f;   // 1/sqrt(32)
  int d = lane & 31;
  int half = lane >> 5;
  bool isV = (lane >= 32);
  #pragma unroll
  for(int hh = 0; hh < 2; hh++){
    int h = wv * 2 + hh;
    int widx = (((b << 3) + h) << 10) + i;
    const float* Kb = kf + ((size_t)(b << 10)) * 256 + h * 32 + d;
    const u16*   Vb = vb + ((size_t)(b << 10)) * 256 + h * 32 + d;
    float q_d = qs[h * 32 + d];
    float S = 0.f, o = 0.f, fp = 0.f;
    if(cnt > 0 && cnt <= 64){
      // ---- e-prefetch: all gathers in one instruction
      for(int s = lane; s < cnt; s += 64)
        evl[wv][s] = ea[(size_t)widx * 1024 + nlist[s]];
      __builtin_amdgcn_wave_barrier();
      // ---- pair scores: half 0 -> slot u, half 1 -> slot u+1; 5-step butterfly
      for(int u = 0; u < cnt; u += 2){
        int s = u + half;
        bool valid = (s < cnt);
        int j = nlist[valid ? s : u];
        float prod = Kb[(size_t)j * 256] * q_d;
        #pragma unroll
        for(int off = 16; off >= 1; off >>= 1) prod += __shfl_xor(prod, off, 64);
        if((lane & 31) == 0 && valid)
          sc[wv][s] = prod * scale + evl[wv][s];
      }
      __builtin_amdgcn_wave_barrier();
      // ---- softmax per-lane from LDS (no cross-lane broadcasts)
      float m = -3.0e38f;
      for(int s = 0; s < cnt; s++) m = fmaxf(m, sc[wv][s]);
      for(int s = 0; s < cnt; s++) fp += evl[wv][s];
      for(int s = half; s < cnt; s += 2){
        float p = __expf(sc[wv][s] - m);
        S += p;
        o = fmaf(p, b2f(Vb[(size_t)nlist[s] * 256]), o);
      }
      o += __shfl_xor(o, 32, 64);
      S += __shfl_xor(S, 32, 64);
      if(lane < 32) aos[h * 32 + d] = o / S;
      if(lane == 0) fs[h] = fp / (float)cnt;
    } else if(cnt > 64){
      // ---- fallback: R12-verbatim online softmax (never hit at 2% density)
      float m = -3.0e38f;
      for(int idx = 0; idx < cnt; idx++){
        int j = nlist[idx];
        float kv = isV ? b2f(Vb[(size_t)j * 256]) : Kb[(size_t)j * 256];
        float prod = isV ? 0.f : kv * q_d;
        #pragma unroll
        for(int off = 16; off >= 1; off >>= 1) prod += __shfl_xor(prod, off, 64);
        float e = ea[(size_t)widx * 1024 + j];
        float s = __shfl(prod, 0, 64) * scale + e;
        float nm = fmaxf(m, s);
        float rs = __expf(m - nm);
        float p  = __expf(s - nm);
        S = S * rs + p;
        o = o * rs + p * (isV ? kv : 0.f);
        m = nm;
        fp += e;
      }
      if(isV) aos[h * 32 + d] = o / S;
      if(lane == 0) fs[h] = fp / (float)cnt;
    } else {
      // zero-degree: softmax over all -1e9 == uniform -> mean of V; f = 0
      S = 1024.f;
      for(int j2 = half; j2 < 1024; j2 += 2)
        o += b2f(Vb[(size_t)j2 * 256]);
      o += __shfl_xor(o, 32, 64);
      if(lane < 32) aos[h * 32 + d] = o / S;
      if(lane == 0) fs[h] = 0.f;
    }
  }
  __syncthreads();
  // ---- epilogue: x + aos@Wo + fs@Wf with 4 independent accumulators
  const float* Wcol = Wo + t;
  float r0 = x[(size_t)bi * 256 + t], r1 = 0.f, r2 = 0.f, r3 = 0.f;
  #pragma unroll 4
  for(int k = 0; k < 256; k += 4){
    r0 = fmaf(aos[k],     Wcol[(size_t)k * 256],       r0);
    r1 = fmaf(aos[k + 1], Wcol[(size_t)(k + 1) * 256], r1);
    r2 = fmaf(aos[k + 2], Wcol[(size_t)(k + 2) * 256], r2);
    r3 = fmaf(aos[k + 3], Wcol[(size_t)(k + 3) * 256], r3);
  }
  float res = (r0 + r1) + (r2 + r3);
  #pragma unroll
  for(int h = 0; h < 8; h++) res = fmaf(fs[h], Wf[(size_t)h * 256 + t], res);
  x2[(size_t)bi * 256 + t] = res;
}

extern "C" void kernel_launch(void* const* d_in, const int* in_sizes, int n_in,
                              void* d_out, int out_size, void* d_ws, size_t ws_size,
                              hipStream_t stream) {
  float* out = (float*)d_out;
  float* x2   = out;                 // [4,1024,256]    f32
  float* ab   = out + 1048576;       // [4,8,1024,1024] f32
  float* expl = out + 34603008;      // [4,1024,1024]   f32 (1.0/0.0)

  bool ok = (n_in == 9) &&
            in_sizes[0] == 1048576  &&
            in_sizes[1] == 4194304  &&
            in_sizes[2] == 33554432 &&
            in_sizes[3] == 65536 && in_sizes[4] == 65536 &&
            in_sizes[5] == 65536 && in_sizes[6] == 65536 &&
            in_sizes[7] == 2048  && in_sizes[8] == 64 &&
            out_size == 38797312;
  if(!ok){
    hipLaunchKernelGGL(k_fill, dim3(4096), dim3(256), 0, stream, x2, 1048576u, 1000.0f);
    return;
  }
  if(ws_size < (size_t)15335424){
    hipLaunchKernelGGL(k_fill, dim3(4096), dim3(256), 0, stream, x2, 1048576u, 2000.0f);
    return;
  }

  const float* x   = (const float*)d_in[0];
  const int*   adj = (const int*)d_in[1];
  const float* ea  = (const float*)d_in[2];
  const float* Wq  = (const float*)d_in[3];
  const float* Wk  = (const float*)d_in[4];
  const float* Wv  = (const float*)d_in[5];
  const float* Wo  = (const float*)d_in[6];
  const float* Wf  = (const float*)d_in[7];
  const float* dw  = (const float*)d_in[8];

  char* ws = (char*)d_ws;
  u64*   bits  = (u64*)(ws + 0);           //  512 KB [0, 524288)
  u8*    dist  = (u8*)(ws + 524288);       //    4 MB [524288, 4718592)
  float* qf    = (float*)(ws + 4718592);   //    4 MB [4718592, 8912896)
  float* kf    = (float*)(ws + 8912896);   //    4 MB [8912896, 13107200)
  u16*   vb    = (u16*)(ws + 13107200);    //    2 MB [13107200, 15204352)
  float* fvals = (float*)(ws + 15204352);  //  128 KB -> 15335424 (written, unused)

  hipLaunchKernelGGL(k_bitset,    dim3(1024), dim3(256), 0, stream, adj, bits);
  hipLaunchKernelGGL(k_bfs,       dim3(4096), dim3(64),  0, stream, bits, dist, expl);
  hipLaunchKernelGGL(k_bias,      dim3(8192), dim3(256), 0, stream, ea, dist, dw, ab, fvals);
  hipLaunchKernelGGL(k_proj3,     dim3(384),  dim3(256), 0, stream, x, Wq, Wk, Wv, qf, kf, vb);
  hipLaunchKernelGGL(k_fusedattn, dim3(4096), dim3(256), 0, stream,
                     x, adj, ea, qf, kf, vb, Wo, Wf, x2);
}